// Round 10
// baseline (117.877 us; speedup 1.0000x reference)
//
#include <hip/hip_runtime.h>

typedef _Float16 h16x8 __attribute__((ext_vector_type(8)));
typedef _Float16 h16x4 __attribute__((ext_vector_type(4)));
typedef _Float16 h16x2 __attribute__((ext_vector_type(2)));
typedef float    fx4   __attribute__((ext_vector_type(4)));

static __device__ __forceinline__ fx4 mfma16(h16x8 a, h16x8 b, fx4 c) {
  return __builtin_amdgcn_mfma_f32_16x16x32_f16(a, b, c, 0, 0, 0);
}
static __device__ __forceinline__ h16x2 pkrtz(float a, float b) {
  auto r = __builtin_amdgcn_cvt_pkrtz(a, b);        // v_cvt_pkrtz_f16_f32
  h16x2 o; __builtin_memcpy(&o, &r, sizeof(o)); return o;
}
union ABfrag { h16x2 p[4]; h16x8 v; };
union H4     { h16x2 p[2]; h16x4 v; };

// R10: depth-1 acc pipeline was NEUTRAL (R9) -> dropped (frees 24 VGPR).
// Recalibrated model: 16x16x32 MFMA is ~19.4 cyc per SIMD (m06 per-CU figure
// /4) -> MFMA pipe ~9.6us/SIMD is the structural floor at 4 waves/SIMD; the
// rest is VALU + stalls. This round: (a) 4-obstacle register batches — one
// ds_read_b128 feeds 4 independent L1->MFMA->pool chains (in-loop LDS ops
// halve, compiler interleaves chains for ILP); (b) packed-f32 pooling
// (pk_max/pk_add, no in-loop pkrtz); (c) bias acc-init hoisted to persistent
// regs. VGPR ~115 < 128 cap; occupancy unchanged (2 blocks/CU via LDS).
// Retained: block-shared LDS weight tiles (R7), weights from d_in (d_ws is
// uncached — R4), (512,4) -> 128-VGPR cap no spills (R5/R6).
//
// Transpose permutation: writer (lane c, col-tile ct) stores feature f=16*ct+c
// at position p=4*c+ct (one ds_write_b64); consumer weight rows are staged at
// f = 16*(p&3)+(p>>2) so K-order matches (dot products are order-invariant).

__global__ __launch_bounds__(512, 4)
void deepset_main(const float* __restrict__ x,   const float* __restrict__ vel,
                  const float* __restrict__ pW1, const float* __restrict__ pb1,
                  const float* __restrict__ pW2, const float* __restrict__ pb2,
                  const float* __restrict__ pW3, const float* __restrict__ pb3,
                  const float* __restrict__ rW1, const float* __restrict__ rb1,
                  const float* __restrict__ rW2, const float* __restrict__ rb2,
                  const float* __restrict__ rW3, const float* __restrict__ rb3,
                  float* __restrict__ out)
{
  __shared__ __align__(16) _Float16 L2T[64][72];   // phi W2, natural rows
  __shared__ __align__(16) _Float16 L3T[64][72];   // phi W3, permuted rows
  __shared__ __align__(16) _Float16 Q1T[64][72];   // rho W1, permuted rows
  __shared__ __align__(16) _Float16 Q2T[64][72];   // rho W2, permuted rows
  __shared__ __align__(16) _Float16 Q3T[32][72];   // rho W3, permuted rows
  __shared__ __align__(16) _Float16 xh[8][16][72]; // per-wave x tile / transpose buf

  const int tid  = threadIdx.x;
  const int wave = tid >> 6;
  const int lane = tid & 63;
  const int q    = lane >> 4;
  const int c    = lane & 15;
  const int sBase = blockIdx.x * 128;
  const int sWave = sBase + wave * 16;

  // ---- cooperative weight staging: coalesced row loads, b128 LDS writes.
  {
    const int col = tid & 63;
    const int kg  = tid >> 6;
    float v2[8], v3[8], r1[8], r2[8];
#pragma unroll
    for (int j = 0; j < 8; ++j) {
      const int p = 8*kg + j;
      const int f = 16*(p & 3) + (p >> 2);         // permuted source row
      v2[j] = pW2[p*64 + col];
      v3[j] = pW3[f*64 + col];
      r1[j] = rW1[f*64 + col];
      r2[j] = rW2[f*64 + col];
    }
    h16x8 h2v, h3v, h1v, h2r;
#pragma unroll
    for (int j = 0; j < 8; ++j) { h2v[j] = (_Float16)v2[j]; h3v[j] = (_Float16)v3[j];
                                  h1v[j] = (_Float16)r1[j]; h2r[j] = (_Float16)r2[j]; }
    *(h16x8*)&L2T[col][8*kg] = h2v;
    *(h16x8*)&L3T[col][8*kg] = h3v;
    *(h16x8*)&Q1T[col][8*kg] = h1v;
    *(h16x8*)&Q2T[col][8*kg] = h2r;
    if (tid < 256) {                               // rho W3 is 64x32
      const int col3 = tid & 31;
      const int kg3  = tid >> 5;
      float r3[8];
#pragma unroll
      for (int j = 0; j < 8; ++j) {
        const int p = 8*kg3 + j;
        const int f = 16*(p & 3) + (p >> 2);
        r3[j] = rW3[f*32 + col3];
      }
      h16x8 h3r;
#pragma unroll
      for (int j = 0; j < 8; ++j) h3r[j] = (_Float16)r3[j];
      *(h16x8*)&Q3T[col3][8*kg3] = h3r;
    }
  }

  // ---- x tile -> per-wave LDS (f16)
  {
    const int s0 = lane >> 2, ch = (lane & 3) * 16;
#pragma unroll
    for (int k = 0; k < 4; ++k) {
      const fx4 g = *(const fx4*)(x + (size_t)(sWave + s0)*64 + ch + 4*k);
      H4 pk; pk.p[0] = pkrtz(g[0], g[1]); pk.p[1] = pkrtz(g[2], g[3]);
      *(h16x4*)&xh[wave][s0][ch + 4*k] = pk.v;
    }
  }
  const float2 vc = *(const float2*)(vel + 2*(size_t)(sWave + c)); // lane's state

  // ---- layer-1 constants (same for all waves -> L2-hot)
  h16x2 wx[2][4], wy[2][4], vbp[2][4];
#pragma unroll
  for (int ks = 0; ks < 2; ++ks)
#pragma unroll
    for (int t = 0; t < 4; ++t) {
      const int f0 = 32*ks + 8*q + 2*t;
      wx[ks][t] = pkrtz(pW1[f0], pW1[f0 + 1]);
      wy[ks][t] = pkrtz(pW1[64 + f0], pW1[64 + f0 + 1]);
      const float v0 = fmaf(vc.x, pW1[128 + f0],     fmaf(vc.y, pW1[192 + f0],     pb1[f0]));
      const float v1 = fmaf(vc.x, pW1[128 + f0 + 1], fmaf(vc.y, pW1[192 + f0 + 1], pb1[f0 + 1]));
      vbp[ks][t] = pkrtz(v0, v1);
    }
  fx4 bias2[4];                             // persistent MFMA acc-init regs
#pragma unroll
  for (int ct = 0; ct < 4; ++ct) {
    const float b = pb2[16*ct + c];
    bias2[ct] = fx4{b, b, b, b};
  }

  __syncthreads();                         // weight tiles + x tiles ready

  // ---- phi W2 B-fragments: one ds_read_b128 each
  h16x8 B2[4][2];
#pragma unroll
  for (int ct = 0; ct < 4; ++ct)
#pragma unroll
    for (int ks = 0; ks < 2; ++ks)
      B2[ct][ks] = *(const h16x8*)&L2T[16*ct + c][32*ks + 8*q];

  const h16x2 z2 = {(_Float16)0.f, (_Float16)0.f};
  const fx4 zf4 = {0.f, 0.f, 0.f, 0.f};
  fx4 Xacc[4] = {zf4, zf4, zf4, zf4};      // f32 pooled X[feat 16ct+c][state 4q+r]

  // ================= phi + pool: 8 groups of 4 register-fed obstacles =======
  h16x8 P_cur = *(const h16x8*)&xh[wave][c][0];    // obstacles 0..3 of state c
#pragma unroll 1
  for (int g = 0; g < 8; ++g) {
    const h16x8 P_nxt = *(const h16x8*)&xh[wave][c][8*((g + 1) & 7)];
#pragma unroll
    for (int j = 0; j < 4; ++j) {          // obstacle 4g+j — independent chains
      h16x2 ox, oy;
      ox[0] = P_cur[2*j];     ox[1] = P_cur[2*j];
      oy[0] = P_cur[2*j + 1]; oy[1] = P_cur[2*j + 1];
      h16x8 A1[2];                         // h1[state=c][k=32ks+8q+jj]
#pragma unroll
      for (int ks = 0; ks < 2; ++ks) {
        ABfrag a;
#pragma unroll
        for (int t = 0; t < 4; ++t) {
          const h16x2 h = ox * wx[ks][t] + oy * wy[ks][t] + vbp[ks][t];
          a.p[t] = __builtin_elementwise_max(h, z2);
        }
        A1[ks] = a.v;
      }
#pragma unroll
      for (int ct = 0; ct < 4; ++ct) {
        fx4 acc = mfma16(A1[0], B2[ct][0], bias2[ct]);
        acc = mfma16(A1[1], B2[ct][1], acc);
        Xacc[ct] += __builtin_elementwise_max(acc, zf4);  // v_pk_max/add_f32
      }
    }
    P_cur = P_nxt;
  }

  // ---- tail: reuse this wave's xh tile as the transpose buffer
  _Float16 (*h2T)[72] = xh[wave];

  // X (C-layout f32) -> permuted transpose write
#pragma unroll
  for (int r = 0; r < 4; ++r) {
    H4 pk;
    pk.p[0] = pkrtz(Xacc[0][r], Xacc[1][r]);
    pk.p[1] = pkrtz(Xacc[2][r], Xacc[3][r]);
    *(h16x4*)&h2T[4*q + r][4*c] = pk.v;
  }
  // phi W3 fragments (permuted rows already staged)
  h16x8 B3[4][2];
#pragma unroll
  for (int ct = 0; ct < 4; ++ct)
#pragma unroll
    for (int ks = 0; ks < 2; ++ks)
      B3[ct][ks] = *(const h16x8*)&L3T[16*ct + c][32*ks + 8*q];
  float b3s[4];
#pragma unroll
  for (int ct = 0; ct < 4; ++ct) b3s[ct] = 32.f * pb3[16*ct + c];

  __builtin_amdgcn_s_waitcnt(0xC07F);      // lgkmcnt(0)
  __builtin_amdgcn_wave_barrier();
  h16x8 AX[2];
#pragma unroll
  for (int ks = 0; ks < 2; ++ks)
    AX[ks] = *(const h16x8*)&h2T[c][32*ks + 8*q];
  __builtin_amdgcn_wave_barrier();

  // phi layer 3 (linear, pooled): X = W3^T(sum relu) + 32*b3
  fx4 C3[4];
#pragma unroll
  for (int ct = 0; ct < 4; ++ct) {
    fx4 acc = {b3s[ct], b3s[ct], b3s[ct], b3s[ct]};
    acc = mfma16(AX[0], B3[ct][0], acc);
    acc = mfma16(AX[1], B3[ct][1], acc);
    C3[ct] = acc;
  }
#pragma unroll
  for (int r = 0; r < 4; ++r) {
    H4 pk;
    pk.p[0] = pkrtz(C3[0][r], C3[1][r]);
    pk.p[1] = pkrtz(C3[2][r], C3[3][r]);
    *(h16x4*)&h2T[4*q + r][4*c] = pk.v;
  }
  h16x8 R1[4][2];
#pragma unroll
  for (int ct = 0; ct < 4; ++ct)
#pragma unroll
    for (int ks = 0; ks < 2; ++ks)
      R1[ct][ks] = *(const h16x8*)&Q1T[16*ct + c][32*ks + 8*q];
  float rb1v[4];
#pragma unroll
  for (int ct = 0; ct < 4; ++ct) rb1v[ct] = rb1[16*ct + c];

  __builtin_amdgcn_s_waitcnt(0xC07F);
  __builtin_amdgcn_wave_barrier();
  h16x8 A1r[2];
#pragma unroll
  for (int ks = 0; ks < 2; ++ks)
    A1r[ks] = *(const h16x8*)&h2T[c][32*ks + 8*q];
  __builtin_amdgcn_wave_barrier();

  // rho layer 1
  fx4 D1[4];
#pragma unroll
  for (int ct = 0; ct < 4; ++ct) {
    fx4 acc = {rb1v[ct], rb1v[ct], rb1v[ct], rb1v[ct]};
    acc = mfma16(A1r[0], R1[ct][0], acc);
    acc = mfma16(A1r[1], R1[ct][1], acc);
    D1[ct] = __builtin_elementwise_max(acc, zf4);
  }
#pragma unroll
  for (int r = 0; r < 4; ++r) {
    H4 pk;
    pk.p[0] = pkrtz(D1[0][r], D1[1][r]);
    pk.p[1] = pkrtz(D1[2][r], D1[3][r]);
    *(h16x4*)&h2T[4*q + r][4*c] = pk.v;
  }
  h16x8 R2[4][2];
#pragma unroll
  for (int ct = 0; ct < 4; ++ct)
#pragma unroll
    for (int ks = 0; ks < 2; ++ks)
      R2[ct][ks] = *(const h16x8*)&Q2T[16*ct + c][32*ks + 8*q];
  float rb2v[4];
#pragma unroll
  for (int ct = 0; ct < 4; ++ct) rb2v[ct] = rb2[16*ct + c];

  __builtin_amdgcn_s_waitcnt(0xC07F);
  __builtin_amdgcn_wave_barrier();
  h16x8 A2r[2];
#pragma unroll
  for (int ks = 0; ks < 2; ++ks)
    A2r[ks] = *(const h16x8*)&h2T[c][32*ks + 8*q];
  __builtin_amdgcn_wave_barrier();

  // rho layer 2
  fx4 D2[4];
#pragma unroll
  for (int ct = 0; ct < 4; ++ct) {
    fx4 acc = {rb2v[ct], rb2v[ct], rb2v[ct], rb2v[ct]};
    acc = mfma16(A2r[0], R2[ct][0], acc);
    acc = mfma16(A2r[1], R2[ct][1], acc);
    D2[ct] = __builtin_elementwise_max(acc, zf4);
  }
#pragma unroll
  for (int r = 0; r < 4; ++r) {
    H4 pk;
    pk.p[0] = pkrtz(D2[0][r], D2[1][r]);
    pk.p[1] = pkrtz(D2[2][r], D2[3][r]);
    *(h16x4*)&h2T[4*q + r][4*c] = pk.v;
  }
  h16x8 R3[2][2];
#pragma unroll
  for (int ct = 0; ct < 2; ++ct)
#pragma unroll
    for (int ks = 0; ks < 2; ++ks)
      R3[ct][ks] = *(const h16x8*)&Q3T[16*ct + c][32*ks + 8*q];
  float rb3v[2];
#pragma unroll
  for (int ct = 0; ct < 2; ++ct) rb3v[ct] = rb3[16*ct + c];

  __builtin_amdgcn_s_waitcnt(0xC07F);
  __builtin_amdgcn_wave_barrier();
  h16x8 A3r[2];
#pragma unroll
  for (int ks = 0; ks < 2; ++ks)
    A3r[ks] = *(const h16x8*)&h2T[c][32*ks + 8*q];
  __builtin_amdgcn_wave_barrier();

  // rho layer 3 + store
  fx4 D3[2];
#pragma unroll
  for (int ct = 0; ct < 2; ++ct) {
    fx4 acc = {rb3v[ct], rb3v[ct], rb3v[ct], rb3v[ct]};
    acc = mfma16(A3r[0], R3[ct][0], acc);
    acc = mfma16(A3r[1], R3[ct][1], acc);
    D3[ct] = acc;
  }
  const int srow = sWave + 4*q;
#pragma unroll
  for (int ct = 0; ct < 2; ++ct)
#pragma unroll
    for (int r = 0; r < 4; ++r)
      out[(size_t)(srow + r)*32 + 16*ct + c] = D3[ct][r];
}

extern "C" void kernel_launch(void* const* d_in, const int* in_sizes, int n_in,
                              void* d_out, int out_size, void* d_ws, size_t ws_size,
                              hipStream_t stream) {
  const float* x   = (const float*)d_in[0];
  const float* vel = (const float*)d_in[1];
  const float* pW1 = (const float*)d_in[2];
  const float* pb1 = (const float*)d_in[3];
  const float* pW2 = (const float*)d_in[4];
  const float* pb2 = (const float*)d_in[5];
  const float* pW3 = (const float*)d_in[6];
  const float* pb3 = (const float*)d_in[7];
  const float* rW1 = (const float*)d_in[8];
  const float* rb1 = (const float*)d_in[9];
  const float* rW2 = (const float*)d_in[10];
  const float* rb2 = (const float*)d_in[11];
  const float* rW3 = (const float*)d_in[12];
  const float* rb3 = (const float*)d_in[13];
  float* out = (float*)d_out;

  const int B = in_sizes[0] / 64;        // x is [B, 64]
  deepset_main<<<dim3(B / 128), dim3(512), 0, stream>>>(
      x, vel, pW1, pb1, pW2, pb2, pW3, pb3,
      rW1, rb1, rW2, rb2, rW3, rb3, out);
}